// Round 1
// 326.657 us; speedup vs baseline: 1.0695x; 1.0695x over previous
//
#include <hip/hip_runtime.h>

typedef unsigned short ushort_t;
typedef float f32x4 __attribute__((ext_vector_type(4)));
typedef short short8 __attribute__((ext_vector_type(8)));

#define B_   32
#define C_   1536
#define N_   576      // H*W = 24*24
#define HID_ 512
#define D_   128
#define K_   64

__device__ __forceinline__ float bf2f(ushort_t u) {
    union { unsigned u; float f; } c; c.u = ((unsigned)u) << 16; return c.f;
}
__device__ __forceinline__ ushort_t f2bf(float x) {
    unsigned u = __float_as_uint(x);
    return (ushort_t)((u + 0x7FFFu + ((u >> 16) & 1u)) >> 16);
}

// async global->LDS, 16B per lane. LDS dest = wave-uniform base + lane*16.
typedef const __attribute__((address_space(1))) char gas_char;
typedef __attribute__((address_space(3))) char las_char;
__device__ __forceinline__ void cp16(const void* g, void* l) {
    __builtin_amdgcn_global_load_lds((gas_char*)(size_t)g,
                                     (las_char*)(unsigned)(size_t)l, 16, 0, 0);
}

// Wb layout: W1cat (1024,1536) = [w1c;w1s] | b1cat (1024) | w2c | b2c | w2s | b2s
#define OB1_  1572864
#define OW2C_ 1573888
#define OB2C_ 1639424
#define OW2S_ 1639552
#define OB2S_ 1672320
#define WTOT_ 1672384
#define TRB_  6912                       // 24*9*32 transpose blocks
#define CVB_  ((WTOT_ + 255) / 256)      // convert blocks

// ---------------------------------------------------------------- prep
// Fused: [0,TRB_) transpose x (B,C,N) -> Xt (B,N,C) bf16;
//        [TRB_, TRB_+CVB_) convert/concat weights to bf16.
__global__ __launch_bounds__(256) void prep_kernel(
    const void* __restrict__ x,
    const void* __restrict__ w1c, const void* __restrict__ b1c,
    const void* __restrict__ w2c, const void* __restrict__ b2c,
    const void* __restrict__ w1s, const void* __restrict__ b1s,
    const void* __restrict__ w2s, const void* __restrict__ b2s,
    const unsigned* __restrict__ temp,
    ushort_t* __restrict__ xt, ushort_t* __restrict__ o, float* __restrict__ Tp)
{
    __shared__ ushort_t t[64][68];
    unsigned d = temp[0];
    int flag = (d == 0x3F800000u) ? 1 : 0;
    int tid = threadIdx.x;
    int idx = blockIdx.x;
    if (idx == 0 && tid == 0)
        *Tp = flag ? __uint_as_float(d) : bf2f((ushort_t)(d & 0xFFFFu));

    if (idx < TRB_) {
        int b = idx / 216, rem = idx % 216;
        int c0 = (rem % 24) * 64, n0 = (rem / 24) * 64;
        ushort_t* xtb = xt + (size_t)b * N_ * C_;
        int r = tid >> 4, c4 = (tid & 15) * 4;
        if (flag) {
            const float* xb = (const float*)x + (size_t)b * C_ * N_;
#pragma unroll
            for (int i = 0; i < 4; ++i) {
                int cc = r + i * 16;
                float4 v = *(const float4*)&xb[(size_t)(c0 + cc) * N_ + n0 + c4];
                t[cc][c4 + 0] = f2bf(v.x);
                t[cc][c4 + 1] = f2bf(v.y);
                t[cc][c4 + 2] = f2bf(v.z);
                t[cc][c4 + 3] = f2bf(v.w);
            }
        } else {
            const ushort_t* xb = (const ushort_t*)x + (size_t)b * C_ * N_;
#pragma unroll
            for (int i = 0; i < 4; ++i) {
                int cc = r + i * 16;
                *(uint2*)&t[cc][c4] =
                    *(const uint2*)&xb[(size_t)(c0 + cc) * N_ + n0 + c4];
            }
        }
        __syncthreads();
#pragma unroll
        for (int i = 0; i < 4; ++i) {
            int nn = r + i * 16;
            ushort_t v0 = t[c4 + 0][nn], v1 = t[c4 + 1][nn];
            ushort_t v2 = t[c4 + 2][nn], v3 = t[c4 + 3][nn];
            uint2 vv;
            vv.x = (unsigned)v0 | ((unsigned)v1 << 16);
            vv.y = (unsigned)v2 | ((unsigned)v3 << 16);
            *(uint2*)&xtb[(size_t)(n0 + nn) * C_ + c0 + c4] = vv;
        }
    } else {
        int i = (idx - TRB_) * 256 + tid;
        if (i >= WTOT_) return;
        const void* p; int off;
        if      (i < 786432)  { p = w1c; off = i; }
        else if (i < OB1_)    { p = w1s; off = i - 786432; }
        else if (i < 1573376) { p = b1c; off = i - OB1_; }
        else if (i < OW2C_)   { p = b1s; off = i - 1573376; }
        else if (i < OB2C_)   { p = w2c; off = i - OW2C_; }
        else if (i < OW2S_)   { p = b2c; off = i - OB2C_; }
        else if (i < OB2S_)   { p = w2s; off = i - OW2S_; }
        else                  { p = b2s; off = i - OB2S_; }
        o[i] = flag ? f2bf(((const float*)p)[off]) : ((const ushort_t*)p)[off];
    }
}

// ---------------------------------------------------------------- gemm1
// Flattened M: h[m][o] = relu(Xt_flat[m,:]·W1cat[o,:] + b1cat[o]),
// m in [0, B*N = 18432 = 144*128): no clamps, no padding waste.
// m97-proven config: 128x128 tile, 256 thr (4 waves 2x2), BK=64 (24 K-steps,
// half the barrier drains of BK=32), cp16 staging with pre-swizzled global
// source (rule #21: linear LDS dest, XOR col chunk with row&7) + matching
// XOR on ds_read -> conflict-free fragment reads.
// Grid 1152 = 144 mt * 8 t, XCD-chunked: each XCD gets 18 consecutive
// M-tiles x all 8 col-tiles (A-panel L2 reuse).
__global__ __launch_bounds__(256) void gemm1_kernel(
    const ushort_t* __restrict__ Xt, const ushort_t* __restrict__ W1,
    const ushort_t* __restrict__ bias, ushort_t* __restrict__ h)
{
    __shared__ ushort_t Atile[128 * 64];   // 16 KB
    __shared__ ushort_t Btile[128 * 64];   // 16 KB
    int idx = blockIdx.x;
    int l = (idx & 7) * 144 + (idx >> 3);    // XCD-chunked logical id
    int mt = l >> 3, t = l & 7;
    int row0 = mt * 128, col0 = t * 128;

    int tid = threadIdx.x, w = tid >> 6, lane = tid & 63;
    int wr = w >> 1, wc = w & 1;
    int r16 = lane & 15, q = lane >> 4, kh = q * 8;

    // staging: sweep s in [0,4): row = s*32 + (tid>>3), chunk (tid&7) XOR row&7
    int srow = tid >> 3;
    int cx = ((tid & 7) ^ (srow & 7)) * 8;   // pre-swizzled source col (elems)
    const ushort_t* ag[4];
    const ushort_t* bg[4];
#pragma unroll
    for (int s = 0; s < 4; ++s) {
        ag[s] = Xt + (size_t)(row0 + s * 32 + srow) * C_ + cx;
        bg[s] = W1 + (size_t)(col0 + s * 32 + srow) * C_ + cx;
    }
    ushort_t* lA = &Atile[tid * 8];
    ushort_t* lB = &Btile[tid * 8];

    f32x4 acc[4][4];
#pragma unroll
    for (int i = 0; i < 4; ++i)
#pragma unroll
        for (int j = 0; j < 4; ++j) acc[i][j] = f32x4{0.f, 0.f, 0.f, 0.f};

    int rowa = wr * 64 + r16;                // +i*16 below; &7 == r16&7
    int rowb = wc * 64 + r16;
    int xr = (r16 & 7) * 8;                  // read-side XOR (elems)

    for (int k0 = 0; k0 < C_; k0 += 64) {
#pragma unroll
        for (int s = 0; s < 4; ++s) {
            cp16(ag[s], lA + s * 2048);
            cp16(bg[s], lB + s * 2048);
            ag[s] += 64; bg[s] += 64;
        }
        __syncthreads();
#pragma unroll
        for (int ks = 0; ks < 2; ++ks) {
            int ke = (ks * 32 + kh) ^ xr;
            short8 af[4], bf[4];
#pragma unroll
            for (int i = 0; i < 4; ++i)
                af[i] = *(const short8*)&Atile[(rowa + i * 16) * 64 + ke];
#pragma unroll
            for (int j = 0; j < 4; ++j)
                bf[j] = *(const short8*)&Btile[(rowb + j * 16) * 64 + ke];
#pragma unroll
            for (int i = 0; i < 4; ++i)
#pragma unroll
                for (int j = 0; j < 4; ++j)
                    acc[i][j] = __builtin_amdgcn_mfma_f32_16x16x32_bf16(
                        af[i], bf[j], acc[i][j], 0, 0, 0);
        }
        __syncthreads();
    }
#pragma unroll
    for (int j = 0; j < 4; ++j) {
        int col = col0 + wc * 64 + j * 16 + r16;
        float cb = bf2f(bias[col]);
#pragma unroll
        for (int i = 0; i < 4; ++i) {
            int rowo = row0 + wr * 64 + i * 16 + q * 4;
#pragma unroll
            for (int r = 0; r < 4; ++r) {
                float v = fmaxf(acc[i][j][r] + cb, 0.f);
                h[(size_t)(rowo + r) * 1024 + col] = f2bf(v);
            }
        }
    }
}

// ---------------------------------------------------------------- gemm2
// z=0: f[c][n] = w2c[c,:]·h[n,0:512] + b2c[c]   (bf16 out, ld N)
// z=1: s[k][n] = w2s[k,:]·h[n,512:1024] + b2s[k] (fp32 out, ld N)
__global__ __launch_bounds__(256) void gemm2_kernel(
    const ushort_t* __restrict__ Wb, const ushort_t* __restrict__ h,
    ushort_t* __restrict__ fbuf, float* __restrict__ sbuf)
{
    __shared__ ushort_t Atile[128 * 32];
    __shared__ ushort_t Btile[128 * 32];
    int nt = blockIdx.x, b = blockIdx.y, z = blockIdx.z;
    int col0 = nt * 128;
    int Mclamp = z ? K_ : D_;
    const ushort_t* Aw   = Wb + (z ? OW2S_ : OW2C_);
    const ushort_t* bias = Wb + (z ? OB2S_ : OB2C_);
    const ushort_t* hb = h + (size_t)b * N_ * 1024 + (z ? 512 : 0);

    int tid = threadIdx.x, w = tid >> 6, lane = tid & 63;
    int wr = w >> 1, wc = w & 1;
    int r16 = lane & 15, q = lane >> 4, kh = q * 8;

    int ar0 = min((tid >> 2), Mclamp - 1);
    int ar1 = min(64 + (tid >> 2), Mclamp - 1);
    const ushort_t* ag0 = Aw + (size_t)ar0 * HID_ + (tid & 3) * 8;
    const ushort_t* ag1 = Aw + (size_t)ar1 * HID_ + (tid & 3) * 8;
    int br0 = min(col0 + (tid >> 2), N_ - 1);
    int br1 = min(col0 + 64 + (tid >> 2), N_ - 1);
    const ushort_t* bg0 = hb + (size_t)br0 * 1024 + (tid & 3) * 8;
    const ushort_t* bg1 = hb + (size_t)br1 * 1024 + (tid & 3) * 8;
    ushort_t* lA0 = &Atile[w * 512];
    ushort_t* lA1 = &Atile[2048 + w * 512];
    ushort_t* lB0 = &Btile[w * 512];
    ushort_t* lB1 = &Btile[2048 + w * 512];

    f32x4 acc[4][4];
#pragma unroll
    for (int i = 0; i < 4; ++i)
#pragma unroll
        for (int j = 0; j < 4; ++j) acc[i][j] = f32x4{0.f, 0.f, 0.f, 0.f};

    for (int k0 = 0; k0 < HID_; k0 += 32) {
        cp16(ag0, lA0); cp16(ag1, lA1);
        cp16(bg0, lB0); cp16(bg1, lB1);
        ag0 += 32; ag1 += 32; bg0 += 32; bg1 += 32;
        __syncthreads();
        short8 af[4], bf[4];
#pragma unroll
        for (int i = 0; i < 4; ++i)
            af[i] = *(const short8*)&Atile[(wr * 64 + i * 16 + r16) * 32 + kh];
#pragma unroll
        for (int j = 0; j < 4; ++j)
            bf[j] = *(const short8*)&Btile[(wc * 64 + j * 16 + r16) * 32 + kh];
#pragma unroll
        for (int i = 0; i < 4; ++i)
#pragma unroll
            for (int j = 0; j < 4; ++j)
                acc[i][j] = __builtin_amdgcn_mfma_f32_16x16x32_bf16(
                    af[i], bf[j], acc[i][j], 0, 0, 0);
        __syncthreads();
    }
#pragma unroll
    for (int j = 0; j < 4; ++j) {
        int col = col0 + wc * 64 + j * 16 + r16;
#pragma unroll
        for (int i = 0; i < 4; ++i) {
            int rowb = wr * 64 + i * 16 + q * 4;
#pragma unroll
            for (int r = 0; r < 4; ++r) {
                int rr = rowb + r;
                if (rr < Mclamp && col < N_) {
                    float v = acc[i][j][r] + bf2f(bias[rr]);
                    if (z == 0)
                        fbuf[(size_t)b * D_ * N_ + (size_t)rr * N_ + col] = f2bf(v);
                    else
                        sbuf[(size_t)b * K_ * N_ + (size_t)rr * N_ + col] = v;
                }
            }
        }
    }
}

// ---------------------------------------------------------------- tail
// One block per batch, now 512 threads (8 waves -> 2 waves/SIMD on the 32
// active CUs, latency hiding for the exp/log chains): Sinkhorn (3 iters) ->
// agg[c][k] = sum_n f[c,n]*P[k,n] with P on the fly (18 K-steps, 8 waves x
// 16 f-rows each) -> block L2 normalize -> store.
__global__ __launch_bounds__(512) void tail_kernel(
    const ushort_t* __restrict__ f_all, const float* __restrict__ s_all,
    const float* __restrict__ Tp, const unsigned* __restrict__ temp,
    void* __restrict__ out)
{
    int b = blockIdx.x;
    const float* S = s_all + (size_t)b * K_ * N_;
    __shared__ float su[K_];
    __shared__ float sv[N_];
    __shared__ ushort_t Ftile[128 * 32];
    __shared__ ushort_t Ptile[64 * 32];
    __shared__ float red[8];
    int tid = threadIdx.x, w = tid >> 6, lane = tid & 63;
    int r16 = lane & 15, q = lane >> 4, kh = q * 8;
    const float norm = -logf((float)N_);

    for (int n = tid; n < N_; n += 512) sv[n] = 0.f;
    __syncthreads();

    for (int it = 0; it < 3; ++it) {
        // u[r] = norm - log(sum_n exp(S[r,n] + v[n])); wave w rows r=w,w+8,..
        for (int r = w; r < K_; r += 8) {
            const float* Sr = S + r * N_;
            float a0 = 0.f, a1 = 0.f, a2 = 0.f;
#pragma unroll
            for (int k = 0; k < 9; k += 3) {
                int n0 = lane + 64 * k;
                a0 += __expf(Sr[n0] + sv[n0]);
                a1 += __expf(Sr[n0 + 64] + sv[n0 + 64]);
                a2 += __expf(Sr[n0 + 128] + sv[n0 + 128]);
            }
            float t = a0 + a1 + a2;
#pragma unroll
            for (int off = 32; off; off >>= 1) t += __shfl_xor(t, off);
            if (lane == 0) su[r] = norm - __logf(t);
        }
        __syncthreads();
        // v[n] = norm - log(sum_m exp(S[m,n] + u[m])); coalesced over n
        for (int n = tid; n < N_; n += 512) {
            const float* Sc = S + n;
            float a0 = 0.f, a1 = 0.f, a2 = 0.f, a3 = 0.f;
#pragma unroll
            for (int m = 0; m < K_; m += 4) {
                a0 += __expf(Sc[(m + 0) * N_] + su[m + 0]);
                a1 += __expf(Sc[(m + 1) * N_] + su[m + 1]);
                a2 += __expf(Sc[(m + 2) * N_] + su[m + 2]);
                a3 += __expf(Sc[(m + 3) * N_] + su[m + 3]);
            }
            sv[n] = norm - __logf((a0 + a1) + (a2 + a3));
        }
        __syncthreads();
    }

    // ---- aggregation with on-the-fly P (512 threads)
    float invT = 1.f / (*Tp);
    const ushort_t* f = f_all + (size_t)b * D_ * N_;
    // F staging: 1 cp16/thread: row tid>>2 (0..127), col chunk (tid&3)*8
    const ushort_t* fg = f + (size_t)(tid >> 2) * N_ + (tid & 3) * 8;
    ushort_t* lF = &Ftile[tid * 8];
    // P compute: 4 elems/thread: row tid>>3 (0..63), cols (tid&7)*4 ..+3
    int prow = tid >> 3, pc0 = (tid & 7) * 4;
    float urow = su[prow];
    const float* Srow = S + (size_t)prow * N_ + pc0;

    f32x4 acc[4];
#pragma unroll
    for (int j = 0; j < 4; ++j) acc[j] = f32x4{0.f, 0.f, 0.f, 0.f};

    for (int s = 0; s < 18; ++s) {
        cp16(fg, lF);
        fg += 32;
        int nb = s * 32;
        ushort_t pv[4];
#pragma unroll
        for (int e = 0; e < 4; ++e) {
            float lp = Srow[e] + urow + sv[nb + pc0 + e] - norm;
            pv[e] = f2bf(__expf(lp * invT) + __expf(lp));
        }
        Srow += 32;
        uint2 w0;
        w0.x = (unsigned)pv[0] | ((unsigned)pv[1] << 16);
        w0.y = (unsigned)pv[2] | ((unsigned)pv[3] << 16);
        *(uint2*)&Ptile[prow * 32 + pc0] = w0;
        __syncthreads();
        short8 af = *(const short8*)&Ftile[(w * 16 + r16) * 32 + kh];
        short8 bf[4];
#pragma unroll
        for (int j = 0; j < 4; ++j)
            bf[j] = *(const short8*)&Ptile[(j * 16 + r16) * 32 + kh];
#pragma unroll
        for (int j = 0; j < 4; ++j)
            acc[j] = __builtin_amdgcn_mfma_f32_16x16x32_bf16(
                af, bf[j], acc[j], 0, 0, 0);
        __syncthreads();
    }

    // ---- block-wide L2 norm + store
    float ssq = 0.f;
#pragma unroll
    for (int j = 0; j < 4; ++j)
#pragma unroll
        for (int r = 0; r < 4; ++r) { float v = acc[j][r]; ssq += v * v; }
#pragma unroll
    for (int off = 32; off; off >>= 1) ssq += __shfl_xor(ssq, off);
    if (lane == 0) red[w] = ssq;
    __syncthreads();
    float tot = (red[0] + red[1] + red[2] + red[3])
              + (red[4] + red[5] + red[6] + red[7]);
    float inv = 1.f / fmaxf(sqrtf(tot), 1e-12f);
    int flag = (temp[0] == 0x3F800000u) ? 1 : 0;
#pragma unroll
    for (int j = 0; j < 4; ++j) {
        int col = j * 16 + r16;
#pragma unroll
        for (int r = 0; r < 4; ++r) {
            int row = w * 16 + q * 4 + r;
            float v = acc[j][r] * inv;
            size_t idx = (size_t)b * D_ * K_ + (size_t)row * K_ + col;
            if (flag) ((float*)out)[idx] = v;
            else      ((ushort_t*)out)[idx] = f2bf(v);
        }
    }
}

extern "C" void kernel_launch(void* const* d_in, const int* in_sizes, int n_in,
                              void* d_out, int out_size, void* d_ws, size_t ws_size,
                              hipStream_t stream) {
    const void* x    = d_in[0];
    const void* w1c  = d_in[1];
    const void* b1c  = d_in[2];
    const void* w2c  = d_in[3];
    const void* b2c  = d_in[4];
    const void* w1s  = d_in[5];
    const void* b1s  = d_in[6];
    const void* w2s  = d_in[7];
    const void* b2s  = d_in[8];
    const unsigned* temp = (const unsigned*)d_in[9];

    char* ws = (char*)d_ws;
    float* Tp = (float*)ws;
    ushort_t* Wb = (ushort_t*)(ws + 256);
    size_t offXt = 256 + (((size_t)WTOT_ * 2 + 255) & ~(size_t)255);
    ushort_t* Xt = (ushort_t*)(ws + offXt);
    size_t xtBytes = (size_t)B_ * N_ * C_ * 2;
    ushort_t* h  = (ushort_t*)(ws + offXt + xtBytes);   // (B*N, 1024) bf16
    // fbuf/sbuf alias the (dead after gemm1) Xt region
    size_t o0 = offXt;
    ushort_t* fbuf = (ushort_t*)(ws + o0);  o0 += (size_t)B_ * D_ * N_ * 2;
    float*    sbuf = (float*)(ws + o0);     o0 += (size_t)B_ * K_ * N_ * 4;

    prep_kernel<<<dim3(TRB_ + CVB_), 256, 0, stream>>>(
        x, w1c, b1c, w2c, b2c, w1s, b1s, w2s, b2s, temp, Xt, Wb, Tp);
    gemm1_kernel<<<dim3(1152), 256, 0, stream>>>(Xt, Wb, Wb + OB1_, h);
    gemm2_kernel<<<dim3(5, B_, 2), 256, 0, stream>>>(Wb, h, fbuf, sbuf);
    tail_kernel<<<dim3(B_), 512, 0, stream>>>(fbuf, sbuf, Tp, temp, (void*)d_out);
}

// Round 2
// 314.748 us; speedup vs baseline: 1.1100x; 1.0378x over previous
//
#include <hip/hip_runtime.h>

typedef unsigned short ushort_t;
typedef float f32x4 __attribute__((ext_vector_type(4)));
typedef short short8 __attribute__((ext_vector_type(8)));

#define B_   32
#define C_   1536
#define N_   576      // H*W = 24*24
#define HID_ 512
#define D_   128
#define K_   64

__device__ __forceinline__ float bf2f(ushort_t u) {
    union { unsigned u; float f; } c; c.u = ((unsigned)u) << 16; return c.f;
}
__device__ __forceinline__ ushort_t f2bf(float x) {
    unsigned u = __float_as_uint(x);
    return (ushort_t)((u + 0x7FFFu + ((u >> 16) & 1u)) >> 16);
}

// async global->LDS, 16B per lane. LDS dest = wave-uniform base + lane*16.
typedef const __attribute__((address_space(1))) char gas_char;
typedef __attribute__((address_space(3))) char las_char;
__device__ __forceinline__ void cp16(const void* g, void* l) {
    __builtin_amdgcn_global_load_lds((gas_char*)(size_t)g,
                                     (las_char*)(unsigned)(size_t)l, 16, 0, 0);
}
// raw barrier with compile-time memory fences (no vmcnt/lgkm drain!)
__device__ __forceinline__ void bar() {
    asm volatile("" ::: "memory");
    __builtin_amdgcn_s_barrier();
    asm volatile("" ::: "memory");
}

// Wb layout: W1cat (1024,1536) = [w1c;w1s] | b1cat (1024) | w2c | b2c | w2s | b2s
#define OB1_  1572864
#define OW2C_ 1573888
#define OB2C_ 1639424
#define OW2S_ 1639552
#define OB2S_ 1672320
#define WTOT_ 1672384
#define TRB_  6912                       // 24*9*32 transpose blocks
#define CVB4_ (((WTOT_ / 4) + 255) / 256)

// ---------------------------------------------------------------- prep
__global__ __launch_bounds__(256) void prep_kernel(
    const void* __restrict__ x,
    const void* __restrict__ w1c, const void* __restrict__ b1c,
    const void* __restrict__ w2c, const void* __restrict__ b2c,
    const void* __restrict__ w1s, const void* __restrict__ b1s,
    const void* __restrict__ w2s, const void* __restrict__ b2s,
    const unsigned* __restrict__ temp,
    ushort_t* __restrict__ xt, ushort_t* __restrict__ o, float* __restrict__ Tp)
{
    __shared__ ushort_t t[64][68];
    unsigned d = temp[0];
    int flag = (d == 0x3F800000u) ? 1 : 0;
    int tid = threadIdx.x;
    int idx = blockIdx.x;
    if (idx == 0 && tid == 0)
        *Tp = flag ? __uint_as_float(d) : bf2f((ushort_t)(d & 0xFFFFu));

    if (idx < TRB_) {
        int b = idx / 216, rem = idx % 216;
        int c0 = (rem % 24) * 64, n0 = (rem / 24) * 64;
        ushort_t* xtb = xt + (size_t)b * N_ * C_;
        int r = tid >> 4, c4 = (tid & 15) * 4;
        if (flag) {
            const float* xb = (const float*)x + (size_t)b * C_ * N_;
#pragma unroll
            for (int i = 0; i < 4; ++i) {
                int cc = r + i * 16;
                float4 v = *(const float4*)&xb[(size_t)(c0 + cc) * N_ + n0 + c4];
                t[cc][c4 + 0] = f2bf(v.x);
                t[cc][c4 + 1] = f2bf(v.y);
                t[cc][c4 + 2] = f2bf(v.z);
                t[cc][c4 + 3] = f2bf(v.w);
            }
        } else {
            const ushort_t* xb = (const ushort_t*)x + (size_t)b * C_ * N_;
#pragma unroll
            for (int i = 0; i < 4; ++i) {
                int cc = r + i * 16;
                *(uint2*)&t[cc][c4] =
                    *(const uint2*)&xb[(size_t)(c0 + cc) * N_ + n0 + c4];
            }
        }
        __syncthreads();
#pragma unroll
        for (int i = 0; i < 4; ++i) {
            int nn = r + i * 16;
            ushort_t v0 = t[c4 + 0][nn], v1 = t[c4 + 1][nn];
            ushort_t v2 = t[c4 + 2][nn], v3 = t[c4 + 3][nn];
            uint2 vv;
            vv.x = (unsigned)v0 | ((unsigned)v1 << 16);
            vv.y = (unsigned)v2 | ((unsigned)v3 << 16);
            *(uint2*)&xtb[(size_t)(n0 + nn) * C_ + c0 + c4] = vv;
        }
    } else {
        int i4 = ((idx - TRB_) * 256 + tid) * 4;
        if (i4 >= WTOT_) return;
        const void* p; int off;
        if      (i4 < 786432)  { p = w1c; off = i4; }
        else if (i4 < OB1_)    { p = w1s; off = i4 - 786432; }
        else if (i4 < 1573376) { p = b1c; off = i4 - OB1_; }
        else if (i4 < OW2C_)   { p = b1s; off = i4 - 1573376; }
        else if (i4 < OB2C_)   { p = w2c; off = i4 - OW2C_; }
        else if (i4 < OW2S_)   { p = b2c; off = i4 - OB2C_; }
        else if (i4 < OB2S_)   { p = w2s; off = i4 - OW2S_; }
        else                   { p = b2s; off = i4 - OB2S_; }
        if (flag) {
            float4 v = *(const float4*)((const float*)p + off);
            uint2 r;
            r.x = (unsigned)f2bf(v.x) | ((unsigned)f2bf(v.y) << 16);
            r.y = (unsigned)f2bf(v.z) | ((unsigned)f2bf(v.w) << 16);
            *(uint2*)&o[i4] = r;
        } else {
            *(uint2*)&o[i4] = *(const uint2*)((const ushort_t*)p + off);
        }
    }
}

// ---------------------------------------------------------------- gemm1
// Flattened M = B*N = 18432 = 144*128. 128x128 tile, BK=64, 24 K-steps.
// 2-phase double-buffered pipeline: stage tile t+1 (8 cp16) -> vmcnt(8)
// (waits ONLY tile t's loads; t+1's stay in flight across the barrier) ->
// raw s_barrier -> ds_read(swz)+MFMA -> raw s_barrier. Last iter peeled
// with vmcnt(0). T2 XOR-swizzle kept (conflicts measured 0).
__global__ __launch_bounds__(256) void gemm1_kernel(
    const ushort_t* __restrict__ Xt, const ushort_t* __restrict__ W1,
    const ushort_t* __restrict__ bias, ushort_t* __restrict__ h)
{
    __shared__ ushort_t Atile[2][128 * 64];   // 32 KB
    __shared__ ushort_t Btile[2][128 * 64];   // 32 KB
    int idx = blockIdx.x;
    int l = (idx & 7) * 144 + (idx >> 3);    // XCD-chunked logical id
    int mt = l >> 3, t = l & 7;
    int row0 = mt * 128, col0 = t * 128;

    int tid = threadIdx.x, w = tid >> 6, lane = tid & 63;
    int wr = w >> 1, wc = w & 1;
    int r16 = lane & 15, q = lane >> 4, kh = q * 8;

    int srow = tid >> 3;
    int cx = ((tid & 7) ^ (srow & 7)) * 8;   // pre-swizzled source col (elems)
    const ushort_t* ag[4];
    const ushort_t* bg[4];
#pragma unroll
    for (int s = 0; s < 4; ++s) {
        ag[s] = Xt + (size_t)(row0 + s * 32 + srow) * C_ + cx;
        bg[s] = W1 + (size_t)(col0 + s * 32 + srow) * C_ + cx;
    }

    f32x4 acc[4][4];
#pragma unroll
    for (int i = 0; i < 4; ++i)
#pragma unroll
        for (int j = 0; j < 4; ++j) acc[i][j] = f32x4{0.f, 0.f, 0.f, 0.f};

    int rowa = wr * 64 + r16;
    int rowb = wc * 64 + r16;
    int xr = (r16 & 7) * 8;                  // read-side XOR (elems)

    auto stage = [&](int buf) {
#pragma unroll
        for (int s = 0; s < 4; ++s) {
            cp16(ag[s], &Atile[buf][tid * 8 + s * 2048]);
            cp16(bg[s], &Btile[buf][tid * 8 + s * 2048]);
            ag[s] += 64; bg[s] += 64;
        }
    };
    auto compute = [&](int cb) {
#pragma unroll
        for (int ks = 0; ks < 2; ++ks) {
            int ke = (ks * 32 + kh) ^ xr;
            short8 af[4], bf[4];
#pragma unroll
            for (int i = 0; i < 4; ++i)
                af[i] = *(const short8*)&Atile[cb][(rowa + i * 16) * 64 + ke];
#pragma unroll
            for (int j = 0; j < 4; ++j)
                bf[j] = *(const short8*)&Btile[cb][(rowb + j * 16) * 64 + ke];
#pragma unroll
            for (int i = 0; i < 4; ++i)
#pragma unroll
                for (int j = 0; j < 4; ++j)
                    acc[i][j] = __builtin_amdgcn_mfma_f32_16x16x32_bf16(
                        af[i], bf[j], acc[i][j], 0, 0, 0);
        }
    };

    stage(0);
    int cur = 0;
    for (int kt = 0; kt < 23; ++kt) {
        stage(cur ^ 1);
        asm volatile("s_waitcnt vmcnt(8)" ::: "memory");
        bar();
        compute(cur);
        bar();
        cur ^= 1;
    }
    asm volatile("s_waitcnt vmcnt(0)" ::: "memory");
    bar();
    compute(cur);

#pragma unroll
    for (int j = 0; j < 4; ++j) {
        int col = col0 + wc * 64 + j * 16 + r16;
        float cb = bf2f(bias[col]);
#pragma unroll
        for (int i = 0; i < 4; ++i) {
            int rowo = row0 + wr * 64 + i * 16 + q * 4;
#pragma unroll
            for (int r = 0; r < 4; ++r) {
                float v = fmaxf(acc[i][j][r] + cb, 0.f);
                h[(size_t)(rowo + r) * 1024 + col] = f2bf(v);
            }
        }
    }
}

// ---------------------------------------------------------------- gemm2
// Same 2-phase pipeline, BK=32, 16 K-steps, vmcnt(4). 4-chunk XOR swizzle.
__global__ __launch_bounds__(256) void gemm2_kernel(
    const ushort_t* __restrict__ Wb, const ushort_t* __restrict__ h,
    ushort_t* __restrict__ fbuf, float* __restrict__ sbuf)
{
    __shared__ ushort_t Atile[2][128 * 32];
    __shared__ ushort_t Btile[2][128 * 32];
    int nt = blockIdx.x, b = blockIdx.y, z = blockIdx.z;
    int col0 = nt * 128;
    int Mclamp = z ? K_ : D_;
    const ushort_t* Aw   = Wb + (z ? OW2S_ : OW2C_);
    const ushort_t* bias = Wb + (z ? OB2S_ : OB2C_);
    const ushort_t* hb = h + (size_t)b * N_ * 1024 + (z ? 512 : 0);

    int tid = threadIdx.x, w = tid >> 6, lane = tid & 63;
    int wr = w >> 1, wc = w & 1;
    int r16 = lane & 15, q = lane >> 4, kh = q * 8;

    int srow = tid >> 2;
    int swz = ((tid & 3) ^ (srow & 3)) * 8;
    int ar0 = min(srow, Mclamp - 1);
    int ar1 = min(64 + srow, Mclamp - 1);
    const ushort_t* ag0 = Aw + (size_t)ar0 * HID_ + swz;
    const ushort_t* ag1 = Aw + (size_t)ar1 * HID_ + swz;
    int br0 = min(col0 + srow, N_ - 1);
    int br1 = min(col0 + 64 + srow, N_ - 1);
    const ushort_t* bg0 = hb + (size_t)br0 * 1024 + swz;
    const ushort_t* bg1 = hb + (size_t)br1 * 1024 + swz;

    f32x4 acc[4][4];
#pragma unroll
    for (int i = 0; i < 4; ++i)
#pragma unroll
        for (int j = 0; j < 4; ++j) acc[i][j] = f32x4{0.f, 0.f, 0.f, 0.f};

    int xr = (r16 & 3) * 8;

    auto stage = [&](int buf) {
        cp16(ag0, &Atile[buf][tid * 8]);
        cp16(ag1, &Atile[buf][2048 + tid * 8]);
        cp16(bg0, &Btile[buf][tid * 8]);
        cp16(bg1, &Btile[buf][2048 + tid * 8]);
        ag0 += 32; ag1 += 32; bg0 += 32; bg1 += 32;
    };
    auto compute = [&](int cb) {
        int ke = kh ^ xr;
        short8 af[4], bf[4];
#pragma unroll
        for (int i = 0; i < 4; ++i)
            af[i] = *(const short8*)&Atile[cb][(wr * 64 + i * 16 + r16) * 32 + ke];
#pragma unroll
        for (int j = 0; j < 4; ++j)
            bf[j] = *(const short8*)&Btile[cb][(wc * 64 + j * 16 + r16) * 32 + ke];
#pragma unroll
        for (int i = 0; i < 4; ++i)
#pragma unroll
            for (int j = 0; j < 4; ++j)
                acc[i][j] = __builtin_amdgcn_mfma_f32_16x16x32_bf16(
                    af[i], bf[j], acc[i][j], 0, 0, 0);
    };

    stage(0);
    int cur = 0;
    for (int kt = 0; kt < 15; ++kt) {
        stage(cur ^ 1);
        asm volatile("s_waitcnt vmcnt(4)" ::: "memory");
        bar();
        compute(cur);
        bar();
        cur ^= 1;
    }
    asm volatile("s_waitcnt vmcnt(0)" ::: "memory");
    bar();
    compute(cur);

#pragma unroll
    for (int j = 0; j < 4; ++j) {
        int col = col0 + wc * 64 + j * 16 + r16;
#pragma unroll
        for (int i = 0; i < 4; ++i) {
            int rowb = wr * 64 + i * 16 + q * 4;
#pragma unroll
            for (int r = 0; r < 4; ++r) {
                int rr = rowb + r;
                if (rr < Mclamp && col < N_) {
                    float v = acc[i][j][r] + bf2f(bias[rr]);
                    if (z == 0)
                        fbuf[(size_t)b * D_ * N_ + (size_t)rr * N_ + col] = f2bf(v);
                    else
                        sbuf[(size_t)b * K_ * N_ + (size_t)rr * N_ + col] = v;
                }
            }
        }
    }
}

// ---------------------------------------------------------------- sinkhorn
// One block per batch (512 thr), 3 iterations, u/v -> workspace.
__global__ __launch_bounds__(512) void sinkhorn_kernel(
    const float* __restrict__ s_all, float* __restrict__ uv)
{
    int b = blockIdx.x;
    const float* S = s_all + (size_t)b * K_ * N_;
    __shared__ float su[K_];
    __shared__ float sv[N_];
    int tid = threadIdx.x, w = tid >> 6, lane = tid & 63;
    const float norm = -logf((float)N_);

    for (int n = tid; n < N_; n += 512) sv[n] = 0.f;
    __syncthreads();

    for (int it = 0; it < 3; ++it) {
        for (int r = w; r < K_; r += 8) {
            const float* Sr = S + r * N_;
            float a0 = 0.f, a1 = 0.f, a2 = 0.f;
#pragma unroll
            for (int k = 0; k < 9; k += 3) {
                int n0 = lane + 64 * k;
                a0 += __expf(Sr[n0] + sv[n0]);
                a1 += __expf(Sr[n0 + 64] + sv[n0 + 64]);
                a2 += __expf(Sr[n0 + 128] + sv[n0 + 128]);
            }
            float t = a0 + a1 + a2;
#pragma unroll
            for (int off = 32; off; off >>= 1) t += __shfl_xor(t, off);
            if (lane == 0) su[r] = norm - __logf(t);
        }
        __syncthreads();
        for (int n = tid; n < N_; n += 512) {
            const float* Sc = S + n;
            float a0 = 0.f, a1 = 0.f, a2 = 0.f, a3 = 0.f;
#pragma unroll
            for (int m = 0; m < K_; m += 4) {
                a0 += __expf(Sc[(m + 0) * N_] + su[m + 0]);
                a1 += __expf(Sc[(m + 1) * N_] + su[m + 1]);
                a2 += __expf(Sc[(m + 2) * N_] + su[m + 2]);
                a3 += __expf(Sc[(m + 3) * N_] + su[m + 3]);
            }
            sv[n] = norm - __logf((a0 + a1) + (a2 + a3));
        }
        __syncthreads();
    }
    float* ub = uv + (size_t)b * 640;
    if (tid < K_) ub[tid] = su[tid];
    for (int n = tid; n < N_; n += 512) ub[64 + n] = sv[n];
}

// ---------------------------------------------------------------- agg
// grid (8, B): block = 16 f-rows x all K. P (64x32 per step) recomputed
// per block (exp is cheap, parallelism is not). agg fp32 -> workspace.
__global__ __launch_bounds__(256) void agg_kernel(
    const ushort_t* __restrict__ f_all, const float* __restrict__ s_all,
    const float* __restrict__ uv, const float* __restrict__ Tp,
    float* __restrict__ aggws)
{
    int rblk = blockIdx.x;
    int b = blockIdx.y;
    const float* S = s_all + (size_t)b * K_ * N_;
    __shared__ float su[K_];
    __shared__ float sv[N_];
    __shared__ ushort_t Ftile[16 * 32];
    __shared__ ushort_t Ptile[64 * 32];
    int tid = threadIdx.x, w = tid >> 6, lane = tid & 63;
    int r16 = lane & 15, q = lane >> 4;
    const float norm = -logf((float)N_);
    const float* ub = uv + (size_t)b * 640;
    if (tid < K_) su[tid] = ub[tid];
    for (int n = tid; n < N_; n += 256) sv[n] = ub[64 + n];
    __syncthreads();

    float invT = 1.f / (*Tp);
    const ushort_t* f = f_all + (size_t)b * D_ * N_ + (size_t)(rblk * 16) * N_;
    int frow = tid >> 2, fch = tid & 3;
    const ushort_t* fg = f + (size_t)frow * N_ + (size_t)((fch ^ (frow & 3)) * 8);
    int prow = tid >> 2, pc0 = (tid & 3) * 8;
    int pswz = ((tid & 3) ^ (prow & 3)) * 8;
    float urow = su[prow];
    const float* Srow = S + (size_t)prow * N_ + pc0;
    int xa = (q ^ (r16 & 3)) * 8;

    f32x4 acc = f32x4{0.f, 0.f, 0.f, 0.f};

    for (int s = 0; s < 18; ++s) {
        if (tid < 64) cp16(fg, &Ftile[tid * 8]);
        fg += 32;
        int nb = s * 32;
        ushort_t pv[8];
#pragma unroll
        for (int e = 0; e < 8; ++e) {
            float lp = Srow[e] + urow + sv[nb + pc0 + e] - norm;
            pv[e] = f2bf(__expf(lp * invT) + __expf(lp));
        }
        Srow += 32;
        uint2 w0, w1;
        w0.x = (unsigned)pv[0] | ((unsigned)pv[1] << 16);
        w0.y = (unsigned)pv[2] | ((unsigned)pv[3] << 16);
        w1.x = (unsigned)pv[4] | ((unsigned)pv[5] << 16);
        w1.y = (unsigned)pv[6] | ((unsigned)pv[7] << 16);
        *(uint2*)&Ptile[prow * 32 + pswz] = w0;
        *(uint2*)&Ptile[prow * 32 + pswz + 4] = w1;
        __syncthreads();
        short8 af = *(const short8*)&Ftile[r16 * 32 + xa];
        short8 bf = *(const short8*)&Ptile[(w * 16 + r16) * 32 + xa];
        acc = __builtin_amdgcn_mfma_f32_16x16x32_bf16(af, bf, acc, 0, 0, 0);
        __syncthreads();
    }
    float* ao = aggws + (size_t)b * (D_ * K_) + (size_t)(rblk * 16) * K_ + (w * 16 + r16);
#pragma unroll
    for (int r = 0; r < 4; ++r)
        ao[(size_t)(q * 4 + r) * K_] = acc[r];
}

// ---------------------------------------------------------------- norm
// grid B: block-wide L2 norm of agg (128x64) + scaled store to out.
__global__ __launch_bounds__(256) void norm_kernel(
    const float* __restrict__ aggws, const unsigned* __restrict__ temp,
    void* __restrict__ out)
{
    int b = blockIdx.x, tid = threadIdx.x, w = tid >> 6, lane = tid & 63;
    __shared__ float red[4];
    const float4* a4 = (const float4*)(aggws + (size_t)b * (D_ * K_));
    float4 v[8];
    float ssq = 0.f;
#pragma unroll
    for (int i = 0; i < 8; ++i) {
        v[i] = a4[tid + i * 256];
        ssq += v[i].x * v[i].x + v[i].y * v[i].y + v[i].z * v[i].z + v[i].w * v[i].w;
    }
#pragma unroll
    for (int off = 32; off; off >>= 1) ssq += __shfl_xor(ssq, off);
    if (lane == 0) red[w] = ssq;
    __syncthreads();
    float tot = red[0] + red[1] + red[2] + red[3];
    float inv = 1.f / fmaxf(sqrtf(tot), 1e-12f);
    int flag = (temp[0] == 0x3F800000u) ? 1 : 0;
    if (flag) {
        float4* o4 = (float4*)out + (size_t)b * 2048;
#pragma unroll
        for (int i = 0; i < 8; ++i) {
            float4 t = v[i];
            t.x *= inv; t.y *= inv; t.z *= inv; t.w *= inv;
            o4[tid + i * 256] = t;
        }
    } else {
        ushort_t* ob = (ushort_t*)out + (size_t)b * 8192;
#pragma unroll
        for (int i = 0; i < 8; ++i) {
            uint2 p;
            p.x = (unsigned)f2bf(v[i].x * inv) | ((unsigned)f2bf(v[i].y * inv) << 16);
            p.y = (unsigned)f2bf(v[i].z * inv) | ((unsigned)f2bf(v[i].w * inv) << 16);
            *(uint2*)&ob[(size_t)(tid + i * 256) * 4] = p;
        }
    }
}

extern "C" void kernel_launch(void* const* d_in, const int* in_sizes, int n_in,
                              void* d_out, int out_size, void* d_ws, size_t ws_size,
                              hipStream_t stream) {
    const void* x    = d_in[0];
    const void* w1c  = d_in[1];
    const void* b1c  = d_in[2];
    const void* w2c  = d_in[3];
    const void* b2c  = d_in[4];
    const void* w1s  = d_in[5];
    const void* b1s  = d_in[6];
    const void* w2s  = d_in[7];
    const void* b2s  = d_in[8];
    const unsigned* temp = (const unsigned*)d_in[9];

    char* ws = (char*)d_ws;
    float* Tp = (float*)ws;
    ushort_t* Wb = (ushort_t*)(ws + 256);
    size_t offXt = 256 + (((size_t)WTOT_ * 2 + 255) & ~(size_t)255);
    ushort_t* Xt = (ushort_t*)(ws + offXt);
    size_t xtBytes = (size_t)B_ * N_ * C_ * 2;
    size_t hBytes  = (size_t)B_ * N_ * 1024 * 2;
    ushort_t* h  = (ushort_t*)(ws + offXt + xtBytes);   // (B*N, 1024) bf16
    // fbuf/sbuf alias the (dead after gemm1) Xt region
    size_t o0 = offXt;
    ushort_t* fbuf = (ushort_t*)(ws + o0);  o0 += (size_t)B_ * D_ * N_ * 2;
    float*    sbuf = (float*)(ws + o0);     o0 += (size_t)B_ * K_ * N_ * 4;
    float* uvws  = (float*)(ws + offXt + xtBytes + hBytes);
    float* aggws = uvws + (size_t)B_ * 640;

    prep_kernel<<<dim3(TRB_ + CVB4_), 256, 0, stream>>>(
        x, w1c, b1c, w2c, b2c, w1s, b1s, w2s, b2s, temp, Xt, Wb, Tp);
    gemm1_kernel<<<dim3(1152), 256, 0, stream>>>(Xt, Wb, Wb + OB1_, h);
    gemm2_kernel<<<dim3(5, B_, 2), 256, 0, stream>>>(Wb, h, fbuf, sbuf);
    sinkhorn_kernel<<<dim3(B_), 512, 0, stream>>>(sbuf, uvws);
    agg_kernel<<<dim3(8, B_), 256, 0, stream>>>(fbuf, sbuf, uvws, Tp, aggws);
    norm_kernel<<<dim3(B_), 256, 0, stream>>>(aggws, temp, (void*)d_out);
}

// Round 3
// 310.314 us; speedup vs baseline: 1.1258x; 1.0143x over previous
//
#include <hip/hip_runtime.h>

typedef unsigned short ushort_t;
typedef float f32x4 __attribute__((ext_vector_type(4)));
typedef short short8 __attribute__((ext_vector_type(8)));

#define B_   32
#define C_   1536
#define N_   576      // H*W = 24*24
#define HID_ 512
#define D_   128
#define K_   64

__device__ __forceinline__ float bf2f(ushort_t u) {
    union { unsigned u; float f; } c; c.u = ((unsigned)u) << 16; return c.f;
}
__device__ __forceinline__ ushort_t f2bf(float x) {
    unsigned u = __float_as_uint(x);
    return (ushort_t)((u + 0x7FFFu + ((u >> 16) & 1u)) >> 16);
}

// async global->LDS, 16B per lane. LDS dest = wave-uniform base + lane*16.
typedef const __attribute__((address_space(1))) char gas_char;
typedef __attribute__((address_space(3))) char las_char;
__device__ __forceinline__ void cp16(const void* g, void* l) {
    __builtin_amdgcn_global_load_lds((gas_char*)(size_t)g,
                                     (las_char*)(unsigned)(size_t)l, 16, 0, 0);
}
// raw barrier with compile-time memory fences (no vmcnt/lgkm drain!)
__device__ __forceinline__ void bar() {
    asm volatile("" ::: "memory");
    __builtin_amdgcn_s_barrier();
    asm volatile("" ::: "memory");
}

// Wb layout: W1cat (1024,1536) = [w1c;w1s] | b1cat (1024) | w2c | b2c | w2s | b2s
#define OB1_  1572864
#define OW2C_ 1573888
#define OB2C_ 1639424
#define OW2S_ 1639552
#define OB2S_ 1672320
#define WTOT_ 1672384
#define TRB_  6912                       // 24*9*32 transpose blocks
#define CVB4_ (((WTOT_ / 4) + 255) / 256)

// ---------------------------------------------------------------- prep
__global__ __launch_bounds__(256) void prep_kernel(
    const void* __restrict__ x,
    const void* __restrict__ w1c, const void* __restrict__ b1c,
    const void* __restrict__ w2c, const void* __restrict__ b2c,
    const void* __restrict__ w1s, const void* __restrict__ b1s,
    const void* __restrict__ w2s, const void* __restrict__ b2s,
    const unsigned* __restrict__ temp,
    ushort_t* __restrict__ xt, ushort_t* __restrict__ o, float* __restrict__ Tp)
{
    __shared__ ushort_t t[64][68];
    unsigned d = temp[0];
    int flag = (d == 0x3F800000u) ? 1 : 0;
    int tid = threadIdx.x;
    int idx = blockIdx.x;
    if (idx == 0 && tid == 0)
        *Tp = flag ? __uint_as_float(d) : bf2f((ushort_t)(d & 0xFFFFu));

    if (idx < TRB_) {
        int b = idx / 216, rem = idx % 216;
        int c0 = (rem % 24) * 64, n0 = (rem / 24) * 64;
        ushort_t* xtb = xt + (size_t)b * N_ * C_;
        int r = tid >> 4, c4 = (tid & 15) * 4;
        if (flag) {
            const float* xb = (const float*)x + (size_t)b * C_ * N_;
#pragma unroll
            for (int i = 0; i < 4; ++i) {
                int cc = r + i * 16;
                float4 v = *(const float4*)&xb[(size_t)(c0 + cc) * N_ + n0 + c4];
                t[cc][c4 + 0] = f2bf(v.x);
                t[cc][c4 + 1] = f2bf(v.y);
                t[cc][c4 + 2] = f2bf(v.z);
                t[cc][c4 + 3] = f2bf(v.w);
            }
        } else {
            const ushort_t* xb = (const ushort_t*)x + (size_t)b * C_ * N_;
#pragma unroll
            for (int i = 0; i < 4; ++i) {
                int cc = r + i * 16;
                *(uint2*)&t[cc][c4] =
                    *(const uint2*)&xb[(size_t)(c0 + cc) * N_ + n0 + c4];
            }
        }
        __syncthreads();
#pragma unroll
        for (int i = 0; i < 4; ++i) {
            int nn = r + i * 16;
            ushort_t v0 = t[c4 + 0][nn], v1 = t[c4 + 1][nn];
            ushort_t v2 = t[c4 + 2][nn], v3 = t[c4 + 3][nn];
            uint2 vv;
            vv.x = (unsigned)v0 | ((unsigned)v1 << 16);
            vv.y = (unsigned)v2 | ((unsigned)v3 << 16);
            *(uint2*)&xtb[(size_t)(n0 + nn) * C_ + c0 + c4] = vv;
        }
    } else {
        int i4 = ((idx - TRB_) * 256 + tid) * 4;
        if (i4 >= WTOT_) return;
        const void* p; int off;
        if      (i4 < 786432)  { p = w1c; off = i4; }
        else if (i4 < OB1_)    { p = w1s; off = i4 - 786432; }
        else if (i4 < 1573376) { p = b1c; off = i4 - OB1_; }
        else if (i4 < OW2C_)   { p = b1s; off = i4 - 1573376; }
        else if (i4 < OB2C_)   { p = w2c; off = i4 - OW2C_; }
        else if (i4 < OW2S_)   { p = b2c; off = i4 - OB2C_; }
        else if (i4 < OB2S_)   { p = w2s; off = i4 - OW2S_; }
        else                   { p = b2s; off = i4 - OB2S_; }
        if (flag) {
            float4 v = *(const float4*)((const float*)p + off);
            uint2 r;
            r.x = (unsigned)f2bf(v.x) | ((unsigned)f2bf(v.y) << 16);
            r.y = (unsigned)f2bf(v.z) | ((unsigned)f2bf(v.w) << 16);
            *(uint2*)&o[i4] = r;
        } else {
            *(uint2*)&o[i4] = *(const uint2*)((const ushort_t*)p + off);
        }
    }
}

// ---------------------------------------------------------------- gemm1
// Flattened M = B*N = 18432 = 144*128. 128x128 tile, BK=64, 24 K-steps.
// 2-phase double-buffered pipeline, counted vmcnt(8), XOR-swizzle (0 conf).
__global__ __launch_bounds__(256) void gemm1_kernel(
    const ushort_t* __restrict__ Xt, const ushort_t* __restrict__ W1,
    const ushort_t* __restrict__ bias, ushort_t* __restrict__ h)
{
    __shared__ ushort_t Atile[2][128 * 64];   // 32 KB
    __shared__ ushort_t Btile[2][128 * 64];   // 32 KB
    int idx = blockIdx.x;
    int l = (idx & 7) * 144 + (idx >> 3);    // XCD-chunked logical id
    int mt = l >> 3, t = l & 7;
    int row0 = mt * 128, col0 = t * 128;

    int tid = threadIdx.x, w = tid >> 6, lane = tid & 63;
    int wr = w >> 1, wc = w & 1;
    int r16 = lane & 15, q = lane >> 4, kh = q * 8;

    int srow = tid >> 3;
    int cx = ((tid & 7) ^ (srow & 7)) * 8;   // pre-swizzled source col (elems)
    const ushort_t* ag[4];
    const ushort_t* bg[4];
#pragma unroll
    for (int s = 0; s < 4; ++s) {
        ag[s] = Xt + (size_t)(row0 + s * 32 + srow) * C_ + cx;
        bg[s] = W1 + (size_t)(col0 + s * 32 + srow) * C_ + cx;
    }

    f32x4 acc[4][4];
#pragma unroll
    for (int i = 0; i < 4; ++i)
#pragma unroll
        for (int j = 0; j < 4; ++j) acc[i][j] = f32x4{0.f, 0.f, 0.f, 0.f};

    int rowa = wr * 64 + r16;
    int rowb = wc * 64 + r16;
    int xr = (r16 & 7) * 8;                  // read-side XOR (elems)

    auto stage = [&](int buf) {
#pragma unroll
        for (int s = 0; s < 4; ++s) {
            cp16(ag[s], &Atile[buf][tid * 8 + s * 2048]);
            cp16(bg[s], &Btile[buf][tid * 8 + s * 2048]);
            ag[s] += 64; bg[s] += 64;
        }
    };
    auto compute = [&](int cb) {
#pragma unroll
        for (int ks = 0; ks < 2; ++ks) {
            int ke = (ks * 32 + kh) ^ xr;
            short8 af[4], bf[4];
#pragma unroll
            for (int i = 0; i < 4; ++i)
                af[i] = *(const short8*)&Atile[cb][(rowa + i * 16) * 64 + ke];
#pragma unroll
            for (int j = 0; j < 4; ++j)
                bf[j] = *(const short8*)&Btile[cb][(rowb + j * 16) * 64 + ke];
#pragma unroll
            for (int i = 0; i < 4; ++i)
#pragma unroll
                for (int j = 0; j < 4; ++j)
                    acc[i][j] = __builtin_amdgcn_mfma_f32_16x16x32_bf16(
                        af[i], bf[j], acc[i][j], 0, 0, 0);
        }
    };

    stage(0);
    int cur = 0;
    for (int kt = 0; kt < 23; ++kt) {
        stage(cur ^ 1);
        asm volatile("s_waitcnt vmcnt(8)" ::: "memory");
        bar();
        compute(cur);
        bar();
        cur ^= 1;
    }
    asm volatile("s_waitcnt vmcnt(0)" ::: "memory");
    bar();
    compute(cur);

#pragma unroll
    for (int j = 0; j < 4; ++j) {
        int col = col0 + wc * 64 + j * 16 + r16;
        float cb = bf2f(bias[col]);
#pragma unroll
        for (int i = 0; i < 4; ++i) {
            int rowo = row0 + wr * 64 + i * 16 + q * 4;
#pragma unroll
            for (int r = 0; r < 4; ++r) {
                float v = fmaxf(acc[i][j][r] + cb, 0.f);
                h[(size_t)(rowo + r) * 1024 + col] = f2bf(v);
            }
        }
    }
}

// ---------------------------------------------------------------- gemm2
// Same 2-phase pipeline, BK=32, 16 K-steps, vmcnt(4). 4-chunk XOR swizzle.
__global__ __launch_bounds__(256) void gemm2_kernel(
    const ushort_t* __restrict__ Wb, const ushort_t* __restrict__ h,
    ushort_t* __restrict__ fbuf, float* __restrict__ sbuf)
{
    __shared__ ushort_t Atile[2][128 * 32];
    __shared__ ushort_t Btile[2][128 * 32];
    int nt = blockIdx.x, b = blockIdx.y, z = blockIdx.z;
    int col0 = nt * 128;
    int Mclamp = z ? K_ : D_;
    const ushort_t* Aw   = Wb + (z ? OW2S_ : OW2C_);
    const ushort_t* bias = Wb + (z ? OB2S_ : OB2C_);
    const ushort_t* hb = h + (size_t)b * N_ * 1024 + (z ? 512 : 0);

    int tid = threadIdx.x, w = tid >> 6, lane = tid & 63;
    int wr = w >> 1, wc = w & 1;
    int r16 = lane & 15, q = lane >> 4, kh = q * 8;

    int srow = tid >> 2;
    int swz = ((tid & 3) ^ (srow & 3)) * 8;
    int ar0 = min(srow, Mclamp - 1);
    int ar1 = min(64 + srow, Mclamp - 1);
    const ushort_t* ag0 = Aw + (size_t)ar0 * HID_ + swz;
    const ushort_t* ag1 = Aw + (size_t)ar1 * HID_ + swz;
    int br0 = min(col0 + srow, N_ - 1);
    int br1 = min(col0 + 64 + srow, N_ - 1);
    const ushort_t* bg0 = hb + (size_t)br0 * 1024 + swz;
    const ushort_t* bg1 = hb + (size_t)br1 * 1024 + swz;

    f32x4 acc[4][4];
#pragma unroll
    for (int i = 0; i < 4; ++i)
#pragma unroll
        for (int j = 0; j < 4; ++j) acc[i][j] = f32x4{0.f, 0.f, 0.f, 0.f};

    int xr = (r16 & 3) * 8;

    auto stage = [&](int buf) {
        cp16(ag0, &Atile[buf][tid * 8]);
        cp16(ag1, &Atile[buf][2048 + tid * 8]);
        cp16(bg0, &Btile[buf][tid * 8]);
        cp16(bg1, &Btile[buf][2048 + tid * 8]);
        ag0 += 32; ag1 += 32; bg0 += 32; bg1 += 32;
    };
    auto compute = [&](int cb) {
        int ke = kh ^ xr;
        short8 af[4], bf[4];
#pragma unroll
        for (int i = 0; i < 4; ++i)
            af[i] = *(const short8*)&Atile[cb][(wr * 64 + i * 16 + r16) * 32 + ke];
#pragma unroll
        for (int j = 0; j < 4; ++j)
            bf[j] = *(const short8*)&Btile[cb][(wc * 64 + j * 16 + r16) * 32 + ke];
#pragma unroll
        for (int i = 0; i < 4; ++i)
#pragma unroll
            for (int j = 0; j < 4; ++j)
                acc[i][j] = __builtin_amdgcn_mfma_f32_16x16x32_bf16(
                    af[i], bf[j], acc[i][j], 0, 0, 0);
    };

    stage(0);
    int cur = 0;
    for (int kt = 0; kt < 15; ++kt) {
        stage(cur ^ 1);
        asm volatile("s_waitcnt vmcnt(4)" ::: "memory");
        bar();
        compute(cur);
        bar();
        cur ^= 1;
    }
    asm volatile("s_waitcnt vmcnt(0)" ::: "memory");
    bar();
    compute(cur);

#pragma unroll
    for (int j = 0; j < 4; ++j) {
        int col = col0 + wc * 64 + j * 16 + r16;
#pragma unroll
        for (int i = 0; i < 4; ++i) {
            int rowb = wr * 64 + i * 16 + q * 4;
#pragma unroll
            for (int r = 0; r < 4; ++r) {
                int rr = rowb + r;
                if (rr < Mclamp && col < N_) {
                    float v = acc[i][j][r] + bf2f(bias[rr]);
                    if (z == 0)
                        fbuf[(size_t)b * D_ * N_ + (size_t)rr * N_ + col] = f2bf(v);
                    else
                        sbuf[(size_t)b * K_ * N_ + (size_t)rr * N_ + col] = v;
                }
            }
        }
    }
}

// ---------------------------------------------------------------- sinkhorn
// One block per batch (512 thr). S (64x576 fp32) lives ENTIRELY in LDS
// (padded ld 577: column pass stride 577%32==1 -> conflict-free). All 6
// logsumexp passes run from LDS instead of L2. At the end, P[k][n] bf16
// (= exp(lp/T)+exp(lp), temperature folded in) is emitted once per batch,
// killing the old 8x-redundant P recompute in agg.
__global__ __launch_bounds__(512) void sinkhorn_kernel(
    const float* __restrict__ s_all, const float* __restrict__ Tp,
    ushort_t* __restrict__ P_all)
{
    int b = blockIdx.x;
    const float* S = s_all + (size_t)b * K_ * N_;
    __shared__ float Sl[K_ * 577];   // 147.7 KB
    __shared__ float su[K_];
    __shared__ float sv[N_];
    int tid = threadIdx.x, w = tid >> 6, lane = tid & 63;
    const float norm = -logf((float)N_);

    // load S into LDS (coalesced float4 reads; LDS addr = w0 + row)
    const float4* S4 = (const float4*)S;
    for (int g = tid; g < (K_ * N_) / 4; g += 512) {
        float4 v = S4[g];
        int w0 = g * 4;
        int r = w0 / N_;
        int base = w0 + r;           // == r*577 + (w0 - r*576)
        Sl[base + 0] = v.x; Sl[base + 1] = v.y;
        Sl[base + 2] = v.z; Sl[base + 3] = v.w;
    }
    for (int n = tid; n < N_; n += 512) sv[n] = 0.f;
    __syncthreads();

    for (int it = 0; it < 3; ++it) {
        // u[r] = norm - log(sum_n exp(S[r,n]+v[n])); wave w rows r=w,w+8,..
        for (int r = w; r < K_; r += 8) {
            const float* Sr = Sl + r * 577;
            float a0 = 0.f, a1 = 0.f, a2 = 0.f;
#pragma unroll
            for (int k = 0; k < 9; k += 3) {
                int n0 = lane + 64 * k;
                a0 += __expf(Sr[n0] + sv[n0]);
                a1 += __expf(Sr[n0 + 64] + sv[n0 + 64]);
                a2 += __expf(Sr[n0 + 128] + sv[n0 + 128]);
            }
            float t = a0 + a1 + a2;
#pragma unroll
            for (int off = 32; off; off >>= 1) t += __shfl_xor(t, off);
            if (lane == 0) su[r] = norm - __logf(t);
        }
        __syncthreads();
        // v[n] = norm - log(sum_m exp(S[m,n]+u[m]))
        for (int n = tid; n < N_; n += 512) {
            const float* Sc = Sl + n;
            float a0 = 0.f, a1 = 0.f, a2 = 0.f, a3 = 0.f;
#pragma unroll
            for (int m = 0; m < K_; m += 4) {
                a0 += __expf(Sc[(m + 0) * 577] + su[m + 0]);
                a1 += __expf(Sc[(m + 1) * 577] + su[m + 1]);
                a2 += __expf(Sc[(m + 2) * 577] + su[m + 2]);
                a3 += __expf(Sc[(m + 3) * 577] + su[m + 3]);
            }
            sv[n] = norm - __logf((a0 + a1) + (a2 + a3));
        }
        __syncthreads();
    }

    // emit P bf16 [k][n] (ld 576), coalesced 2B/lane
    float invT = 1.f / (*Tp);
    ushort_t* Pb = P_all + (size_t)b * K_ * N_;
    for (int r = w; r < K_; r += 8) {
        float ur = su[r];
        const float* Sr = Sl + r * 577;
#pragma unroll
        for (int k = 0; k < 9; ++k) {
            int n0 = lane + 64 * k;
            float lp = Sr[n0] + ur + sv[n0] - norm;
            Pb[r * N_ + n0] = f2bf(__expf(lp * invT) + __expf(lp));
        }
    }
}

// ---------------------------------------------------------------- aggnorm
// One block per batch (256 thr): agg = f (128x576) x P^T (576x64) as a
// clean 9-step BK=64 MFMA GEMM (double-buffered cp16, vmcnt(6), swizzled),
// fused block-wide L2 normalize + store. No clamps (576 = 9*64 exact).
__global__ __launch_bounds__(256) void aggnorm_kernel(
    const ushort_t* __restrict__ f_all, const ushort_t* __restrict__ P_all,
    const unsigned* __restrict__ temp, void* __restrict__ out)
{
    __shared__ ushort_t Atile[2][128 * 64];  // F tiles, 16 KB each
    __shared__ ushort_t Ptile[2][64 * 64];   // P tiles, 8 KB each
    __shared__ float red[4];
    int b = blockIdx.x;
    const ushort_t* F = f_all + (size_t)b * D_ * N_;
    const ushort_t* P = P_all + (size_t)b * K_ * N_;
    int tid = threadIdx.x, w = tid >> 6, lane = tid & 63;
    int wr = w >> 1, wc = w & 1;
    int r16 = lane & 15, q = lane >> 4, kh = q * 8;

    int srow = tid >> 3;                      // 0..31
    int cx = ((tid & 7) ^ (srow & 7)) * 8;    // pre-swizzled source col
    const ushort_t* fg[4];
    const ushort_t* pg[2];
#pragma unroll
    for (int s = 0; s < 4; ++s)
        fg[s] = F + (size_t)(s * 32 + srow) * N_ + cx;
#pragma unroll
    for (int s = 0; s < 2; ++s)
        pg[s] = P + (size_t)(s * 32 + srow) * N_ + cx;

    f32x4 acc[4][2];
#pragma unroll
    for (int i = 0; i < 4; ++i)
#pragma unroll
        for (int j = 0; j < 2; ++j) acc[i][j] = f32x4{0.f, 0.f, 0.f, 0.f};

    int rowa = wr * 64 + r16;
    int rowp = wc * 32 + r16;
    int xr = (r16 & 7) * 8;

    auto stage = [&](int buf) {
#pragma unroll
        for (int s = 0; s < 4; ++s) {
            cp16(fg[s], &Atile[buf][tid * 8 + s * 2048]);
            fg[s] += 64;
        }
#pragma unroll
        for (int s = 0; s < 2; ++s) {
            cp16(pg[s], &Ptile[buf][tid * 8 + s * 2048]);
            pg[s] += 64;
        }
    };
    auto compute = [&](int cb) {
#pragma unroll
        for (int ks = 0; ks < 2; ++ks) {
            int ke = (ks * 32 + kh) ^ xr;
            short8 af[4], pf[2];
#pragma unroll
            for (int i = 0; i < 4; ++i)
                af[i] = *(const short8*)&Atile[cb][(rowa + i * 16) * 64 + ke];
#pragma unroll
            for (int j = 0; j < 2; ++j)
                pf[j] = *(const short8*)&Ptile[cb][(rowp + j * 16) * 64 + ke];
#pragma unroll
            for (int i = 0; i < 4; ++i)
#pragma unroll
                for (int j = 0; j < 2; ++j)
                    acc[i][j] = __builtin_amdgcn_mfma_f32_16x16x32_bf16(
                        af[i], pf[j], acc[i][j], 0, 0, 0);
        }
    };

    stage(0);
    int cur = 0;
    for (int kt = 0; kt < 8; ++kt) {
        stage(cur ^ 1);
        asm volatile("s_waitcnt vmcnt(6)" ::: "memory");
        bar();
        compute(cur);
        bar();
        cur ^= 1;
    }
    asm volatile("s_waitcnt vmcnt(0)" ::: "memory");
    bar();
    compute(cur);

    // block-wide L2 norm + store
    float ssq = 0.f;
#pragma unroll
    for (int i = 0; i < 4; ++i)
#pragma unroll
        for (int j = 0; j < 2; ++j)
#pragma unroll
            for (int r = 0; r < 4; ++r) { float v = acc[i][j][r]; ssq += v * v; }
#pragma unroll
    for (int off = 32; off; off >>= 1) ssq += __shfl_xor(ssq, off);
    if (lane == 0) red[w] = ssq;
    __syncthreads();
    float tot = red[0] + red[1] + red[2] + red[3];
    float inv = 1.f / fmaxf(sqrtf(tot), 1e-12f);
    int flag = (temp[0] == 0x3F800000u) ? 1 : 0;
#pragma unroll
    for (int i = 0; i < 4; ++i) {
#pragma unroll
        for (int j = 0; j < 2; ++j) {
            int col = wc * 32 + j * 16 + r16;
#pragma unroll
            for (int r = 0; r < 4; ++r) {
                int row = wr * 64 + i * 16 + q * 4 + r;
                float v = acc[i][j][r] * inv;
                size_t idx = (size_t)b * D_ * K_ + (size_t)row * K_ + col;
                if (flag) ((float*)out)[idx] = v;
                else      ((ushort_t*)out)[idx] = f2bf(v);
            }
        }
    }
}

extern "C" void kernel_launch(void* const* d_in, const int* in_sizes, int n_in,
                              void* d_out, int out_size, void* d_ws, size_t ws_size,
                              hipStream_t stream) {
    const void* x    = d_in[0];
    const void* w1c  = d_in[1];
    const void* b1c  = d_in[2];
    const void* w2c  = d_in[3];
    const void* b2c  = d_in[4];
    const void* w1s  = d_in[5];
    const void* b1s  = d_in[6];
    const void* w2s  = d_in[7];
    const void* b2s  = d_in[8];
    const unsigned* temp = (const unsigned*)d_in[9];

    char* ws = (char*)d_ws;
    float* Tp = (float*)ws;
    ushort_t* Wb = (ushort_t*)(ws + 256);
    size_t offXt = 256 + (((size_t)WTOT_ * 2 + 255) & ~(size_t)255);
    ushort_t* Xt = (ushort_t*)(ws + offXt);
    size_t xtBytes = (size_t)B_ * N_ * C_ * 2;
    ushort_t* h  = (ushort_t*)(ws + offXt + xtBytes);   // (B*N, 1024) bf16
    // fbuf/sbuf/P alias the (dead after gemm1) Xt region
    size_t o0 = offXt;
    ushort_t* fbuf = (ushort_t*)(ws + o0);  o0 += (size_t)B_ * D_ * N_ * 2;
    float*    sbuf = (float*)(ws + o0);     o0 += (size_t)B_ * K_ * N_ * 4;
    ushort_t* Pws  = (ushort_t*)(ws + o0);  o0 += (size_t)B_ * K_ * N_ * 2;

    prep_kernel<<<dim3(TRB_ + CVB4_), 256, 0, stream>>>(
        x, w1c, b1c, w2c, b2c, w1s, b1s, w2s, b2s, temp, Xt, Wb, Tp);
    gemm1_kernel<<<dim3(1152), 256, 0, stream>>>(Xt, Wb, Wb + OB1_, h);
    gemm2_kernel<<<dim3(5, B_, 2), 256, 0, stream>>>(Wb, h, fbuf, sbuf);
    sinkhorn_kernel<<<dim3(B_), 512, 0, stream>>>(sbuf, Tp, Pws);
    aggnorm_kernel<<<dim3(B_), 256, 0, stream>>>(fbuf, Pws, temp, (void*)d_out);
}

// Round 4
// 302.378 us; speedup vs baseline: 1.1554x; 1.0262x over previous
//
#include <hip/hip_runtime.h>

typedef unsigned short ushort_t;
typedef float f32x4 __attribute__((ext_vector_type(4)));
typedef short short8 __attribute__((ext_vector_type(8)));

#define B_   32
#define C_   1536
#define N_   576      // H*W = 24*24
#define HID_ 512
#define D_   128
#define K_   64

__device__ __forceinline__ float bf2f(ushort_t u) {
    union { unsigned u; float f; } c; c.u = ((unsigned)u) << 16; return c.f;
}
__device__ __forceinline__ ushort_t f2bf(float x) {
    unsigned u = __float_as_uint(x);
    return (ushort_t)((u + 0x7FFFu + ((u >> 16) & 1u)) >> 16);
}

// async global->LDS, 16B per lane. LDS dest = wave-uniform base + lane*16.
typedef const __attribute__((address_space(1))) char gas_char;
typedef __attribute__((address_space(3))) char las_char;
__device__ __forceinline__ void cp16(const void* g, void* l) {
    __builtin_amdgcn_global_load_lds((gas_char*)(size_t)g,
                                     (las_char*)(unsigned)(size_t)l, 16, 0, 0);
}
// raw barrier with compile-time memory fences (no vmcnt/lgkm drain!)
__device__ __forceinline__ void bar() {
    asm volatile("" ::: "memory");
    __builtin_amdgcn_s_barrier();
    asm volatile("" ::: "memory");
}

// Wb layout: W1cat (1024,1536) = [w1c;w1s] | b1cat (1024) | w2c | b2c | w2s | b2s
#define OB1_  1572864
#define OW2C_ 1573888
#define OB2C_ 1639424
#define OW2S_ 1639552
#define OB2S_ 1672320
#define WTOT_ 1672384
#define TRB2_ 3456                       // 12*9*32 transpose blocks (128c x 64n)
#define CVB4_ (((WTOT_ / 4) + 255) / 256)

// ---------------------------------------------------------------- prep
// Transpose x (B,C,N) -> Xt (B,N,C) bf16 with 128(C)x64(N) tiles:
// fp32 reads 256B runs, bf16 writes 256B runs (uint4/lane).
__global__ __launch_bounds__(256) void prep_kernel(
    const void* __restrict__ x,
    const void* __restrict__ w1c, const void* __restrict__ b1c,
    const void* __restrict__ w2c, const void* __restrict__ b2c,
    const void* __restrict__ w1s, const void* __restrict__ b1s,
    const void* __restrict__ w2s, const void* __restrict__ b2s,
    const unsigned* __restrict__ temp,
    ushort_t* __restrict__ xt, ushort_t* __restrict__ o, float* __restrict__ Tp)
{
    __shared__ ushort_t t[128][65];
    unsigned d = temp[0];
    int flag = (d == 0x3F800000u) ? 1 : 0;
    int tid = threadIdx.x;
    int idx = blockIdx.x;
    if (idx == 0 && tid == 0)
        *Tp = flag ? __uint_as_float(d) : bf2f((ushort_t)(d & 0xFFFFu));

    if (idx < TRB2_) {
        int b = idx / 108, rem = idx % 108;
        int c0 = (rem % 12) * 128, n0 = (rem / 12) * 64;
        ushort_t* xtb = xt + (size_t)b * N_ * C_;
        int r = tid >> 4, n4 = (tid & 15) * 4;
        if (flag) {
            const float* xb = (const float*)x + (size_t)b * C_ * N_;
#pragma unroll
            for (int i = 0; i < 8; ++i) {
                int cc = r + i * 16;
                float4 v = *(const float4*)&xb[(size_t)(c0 + cc) * N_ + n0 + n4];
                t[cc][n4 + 0] = f2bf(v.x);
                t[cc][n4 + 1] = f2bf(v.y);
                t[cc][n4 + 2] = f2bf(v.z);
                t[cc][n4 + 3] = f2bf(v.w);
            }
        } else {
            const ushort_t* xb = (const ushort_t*)x + (size_t)b * C_ * N_;
#pragma unroll
            for (int i = 0; i < 8; ++i) {
                int cc = r + i * 16;
                *(uint2*)&t[cc][n4] =
                    *(const uint2*)&xb[(size_t)(c0 + cc) * N_ + n0 + n4];
            }
        }
        __syncthreads();
        int c8 = (tid & 15) * 8;
#pragma unroll
        for (int i = 0; i < 4; ++i) {
            int nn = r + i * 16;
            ushort_t vv[8];
#pragma unroll
            for (int j = 0; j < 8; ++j) vv[j] = t[c8 + j][nn];
            uint4 o4;
            o4.x = (unsigned)vv[0] | ((unsigned)vv[1] << 16);
            o4.y = (unsigned)vv[2] | ((unsigned)vv[3] << 16);
            o4.z = (unsigned)vv[4] | ((unsigned)vv[5] << 16);
            o4.w = (unsigned)vv[6] | ((unsigned)vv[7] << 16);
            *(uint4*)&xtb[(size_t)(n0 + nn) * C_ + c0 + c8] = o4;
        }
    } else {
        int i4 = ((idx - TRB2_) * 256 + tid) * 4;
        if (i4 >= WTOT_) return;
        const void* p; int off;
        if      (i4 < 786432)  { p = w1c; off = i4; }
        else if (i4 < OB1_)    { p = w1s; off = i4 - 786432; }
        else if (i4 < 1573376) { p = b1c; off = i4 - OB1_; }
        else if (i4 < OW2C_)   { p = b1s; off = i4 - 1573376; }
        else if (i4 < OB2C_)   { p = w2c; off = i4 - OW2C_; }
        else if (i4 < OW2S_)   { p = b2c; off = i4 - OB2C_; }
        else if (i4 < OB2S_)   { p = w2s; off = i4 - OW2S_; }
        else                   { p = b2s; off = i4 - OB2S_; }
        if (flag) {
            float4 v = *(const float4*)((const float*)p + off);
            uint2 r;
            r.x = (unsigned)f2bf(v.x) | ((unsigned)f2bf(v.y) << 16);
            r.y = (unsigned)f2bf(v.z) | ((unsigned)f2bf(v.w) << 16);
            *(uint2*)&o[i4] = r;
        } else {
            *(uint2*)&o[i4] = *(const uint2*)((const ushort_t*)p + off);
        }
    }
}

// ---------------------------------------------------------------- gemm1
// Flattened M = B*N = 18432 = 144*128. 128x128 tile, BK=64, 24 K-steps.
// 2-phase dbuf pipeline, counted vmcnt(8), XOR-swizzle (0 conflicts).
// K-loop FULLY UNROLLED: cp16 global addrs = fixed base + literal (folds
// into 13-bit imm), ds_read addrs = base + 16-bit literal -> per-step VALU
// collapses to ~nothing (was 39% VALUBusy).
__global__ __launch_bounds__(256) void gemm1_kernel(
    const ushort_t* __restrict__ Xt, const ushort_t* __restrict__ W1,
    const ushort_t* __restrict__ bias, ushort_t* __restrict__ h)
{
    __shared__ ushort_t Atile[2][128 * 64];   // 32 KB
    __shared__ ushort_t Btile[2][128 * 64];   // 32 KB
    int idx = blockIdx.x;
    int l = (idx & 7) * 144 + (idx >> 3);    // XCD-chunked logical id
    int mt = l >> 3, t = l & 7;
    int row0 = mt * 128, col0 = t * 128;

    int tid = threadIdx.x, w = tid >> 6, lane = tid & 63;
    int wr = w >> 1, wc = w & 1;
    int r16 = lane & 15, q = lane >> 4, kh = q * 8;

    int srow = tid >> 3;
    int cx = ((tid & 7) ^ (srow & 7)) * 8;   // pre-swizzled source col (elems)
    const ushort_t* ag[4];
    const ushort_t* bg[4];
#pragma unroll
    for (int s = 0; s < 4; ++s) {
        ag[s] = Xt + (size_t)(row0 + s * 32 + srow) * C_ + cx;
        bg[s] = W1 + (size_t)(col0 + s * 32 + srow) * C_ + cx;
    }

    f32x4 acc[4][4];
#pragma unroll
    for (int i = 0; i < 4; ++i)
#pragma unroll
        for (int j = 0; j < 4; ++j) acc[i][j] = f32x4{0.f, 0.f, 0.f, 0.f};

    int rowa = wr * 64 + r16;
    int rowb = wc * 64 + r16;
    int xr = (r16 & 7) * 8;                  // read-side XOR (elems)

    auto stage = [&](int buf, int koff) {    // koff: literal after unroll
#pragma unroll
        for (int s = 0; s < 4; ++s) {
            cp16(ag[s] + koff, &Atile[buf][tid * 8 + s * 2048]);
            cp16(bg[s] + koff, &Btile[buf][tid * 8 + s * 2048]);
        }
    };
    auto compute = [&](int cb) {
#pragma unroll
        for (int ks = 0; ks < 2; ++ks) {
            int ke = (ks * 32 + kh) ^ xr;
            short8 af[4], bf[4];
#pragma unroll
            for (int i = 0; i < 4; ++i)
                af[i] = *(const short8*)&Atile[cb][(rowa + i * 16) * 64 + ke];
#pragma unroll
            for (int j = 0; j < 4; ++j)
                bf[j] = *(const short8*)&Btile[cb][(rowb + j * 16) * 64 + ke];
#pragma unroll
            for (int i = 0; i < 4; ++i)
#pragma unroll
                for (int j = 0; j < 4; ++j)
                    acc[i][j] = __builtin_amdgcn_mfma_f32_16x16x32_bf16(
                        af[i], bf[j], acc[i][j], 0, 0, 0);
        }
    };

    stage(0, 0);
#pragma unroll
    for (int kt = 0; kt < 24; ++kt) {
        int buf = kt & 1;
        if (kt < 23) {
            stage(buf ^ 1, (kt + 1) * 64);
            asm volatile("s_waitcnt vmcnt(8)" ::: "memory");
        } else {
            asm volatile("s_waitcnt vmcnt(0)" ::: "memory");
        }
        bar();
        compute(buf);
        bar();
    }

#pragma unroll
    for (int j = 0; j < 4; ++j) {
        int col = col0 + wc * 64 + j * 16 + r16;
        float cb = bf2f(bias[col]);
#pragma unroll
        for (int i = 0; i < 4; ++i) {
            int rowo = row0 + wr * 64 + i * 16 + q * 4;
#pragma unroll
            for (int r = 0; r < 4; ++r) {
                float v = fmaxf(acc[i][j][r] + cb, 0.f);
                h[(size_t)(rowo + r) * 1024 + col] = f2bf(v);
            }
        }
    }
}

// ---------------------------------------------------------------- gemm2
// Same 2-phase pipeline, BK=32, 16 K-steps fully unrolled, vmcnt(4).
__global__ __launch_bounds__(256) void gemm2_kernel(
    const ushort_t* __restrict__ Wb, const ushort_t* __restrict__ h,
    ushort_t* __restrict__ fbuf, float* __restrict__ sbuf)
{
    __shared__ ushort_t Atile[2][128 * 32];
    __shared__ ushort_t Btile[2][128 * 32];
    int nt = blockIdx.x, b = blockIdx.y, z = blockIdx.z;
    int col0 = nt * 128;
    int Mclamp = z ? K_ : D_;
    const ushort_t* Aw   = Wb + (z ? OW2S_ : OW2C_);
    const ushort_t* bias = Wb + (z ? OB2S_ : OB2C_);
    const ushort_t* hb = h + (size_t)b * N_ * 1024 + (z ? 512 : 0);

    int tid = threadIdx.x, w = tid >> 6, lane = tid & 63;
    int wr = w >> 1, wc = w & 1;
    int r16 = lane & 15, q = lane >> 4, kh = q * 8;

    int srow = tid >> 2;
    int swz = ((tid & 3) ^ (srow & 3)) * 8;
    int ar0 = min(srow, Mclamp - 1);
    int ar1 = min(64 + srow, Mclamp - 1);
    const ushort_t* ag0 = Aw + (size_t)ar0 * HID_ + swz;
    const ushort_t* ag1 = Aw + (size_t)ar1 * HID_ + swz;
    int br0 = min(col0 + srow, N_ - 1);
    int br1 = min(col0 + 64 + srow, N_ - 1);
    const ushort_t* bg0 = hb + (size_t)br0 * 1024 + swz;
    const ushort_t* bg1 = hb + (size_t)br1 * 1024 + swz;

    f32x4 acc[4][4];
#pragma unroll
    for (int i = 0; i < 4; ++i)
#pragma unroll
        for (int j = 0; j < 4; ++j) acc[i][j] = f32x4{0.f, 0.f, 0.f, 0.f};

    int xr = (r16 & 3) * 8;

    auto stage = [&](int buf, int koff) {
        cp16(ag0 + koff, &Atile[buf][tid * 8]);
        cp16(ag1 + koff, &Atile[buf][2048 + tid * 8]);
        cp16(bg0 + koff, &Btile[buf][tid * 8]);
        cp16(bg1 + koff, &Btile[buf][2048 + tid * 8]);
    };
    auto compute = [&](int cb) {
        int ke = kh ^ xr;
        short8 af[4], bf[4];
#pragma unroll
        for (int i = 0; i < 4; ++i)
            af[i] = *(const short8*)&Atile[cb][(wr * 64 + i * 16 + r16) * 32 + ke];
#pragma unroll
        for (int j = 0; j < 4; ++j)
            bf[j] = *(const short8*)&Btile[cb][(wc * 64 + j * 16 + r16) * 32 + ke];
#pragma unroll
        for (int i = 0; i < 4; ++i)
#pragma unroll
            for (int j = 0; j < 4; ++j)
                acc[i][j] = __builtin_amdgcn_mfma_f32_16x16x32_bf16(
                    af[i], bf[j], acc[i][j], 0, 0, 0);
    };

    stage(0, 0);
#pragma unroll
    for (int kt = 0; kt < 16; ++kt) {
        int buf = kt & 1;
        if (kt < 15) {
            stage(buf ^ 1, (kt + 1) * 32);
            asm volatile("s_waitcnt vmcnt(4)" ::: "memory");
        } else {
            asm volatile("s_waitcnt vmcnt(0)" ::: "memory");
        }
        bar();
        compute(buf);
        bar();
    }

#pragma unroll
    for (int j = 0; j < 4; ++j) {
        int col = col0 + wc * 64 + j * 16 + r16;
#pragma unroll
        for (int i = 0; i < 4; ++i) {
            int rowb = wr * 64 + i * 16 + q * 4;
#pragma unroll
            for (int r = 0; r < 4; ++r) {
                int rr = rowb + r;
                if (rr < Mclamp && col < N_) {
                    float v = acc[i][j][r] + bf2f(bias[rr]);
                    if (z == 0)
                        fbuf[(size_t)b * D_ * N_ + (size_t)rr * N_ + col] = f2bf(v);
                    else
                        sbuf[(size_t)b * K_ * N_ + (size_t)rr * N_ + col] = v;
                }
            }
        }
    }
}

// ---------------------------------------------------------------- sinkhorn
// One block per batch (512 thr). S (64x576 fp32) entirely in LDS (ld 577).
// Emits P[k][n] bf16 once per batch.
__global__ __launch_bounds__(512) void sinkhorn_kernel(
    const float* __restrict__ s_all, const float* __restrict__ Tp,
    ushort_t* __restrict__ P_all)
{
    int b = blockIdx.x;
    const float* S = s_all + (size_t)b * K_ * N_;
    __shared__ float Sl[K_ * 577];   // 147.7 KB
    __shared__ float su[K_];
    __shared__ float sv[N_];
    int tid = threadIdx.x, w = tid >> 6, lane = tid & 63;
    const float norm = -logf((float)N_);

    const float4* S4 = (const float4*)S;
    for (int g = tid; g < (K_ * N_) / 4; g += 512) {
        float4 v = S4[g];
        int w0 = g * 4;
        int r = w0 / N_;
        int base = w0 + r;           // == r*577 + (w0 - r*576)
        Sl[base + 0] = v.x; Sl[base + 1] = v.y;
        Sl[base + 2] = v.z; Sl[base + 3] = v.w;
    }
    for (int n = tid; n < N_; n += 512) sv[n] = 0.f;
    __syncthreads();

    for (int it = 0; it < 3; ++it) {
        for (int r = w; r < K_; r += 8) {
            const float* Sr = Sl + r * 577;
            float a0 = 0.f, a1 = 0.f, a2 = 0.f;
#pragma unroll
            for (int k = 0; k < 9; k += 3) {
                int n0 = lane + 64 * k;
                a0 += __expf(Sr[n0] + sv[n0]);
                a1 += __expf(Sr[n0 + 64] + sv[n0 + 64]);
                a2 += __expf(Sr[n0 + 128] + sv[n0 + 128]);
            }
            float t = a0 + a1 + a2;
#pragma unroll
            for (int off = 32; off; off >>= 1) t += __shfl_xor(t, off);
            if (lane == 0) su[r] = norm - __logf(t);
        }
        __syncthreads();
        for (int n = tid; n < N_; n += 512) {
            const float* Sc = Sl + n;
            float a0 = 0.f, a1 = 0.f, a2 = 0.f, a3 = 0.f;
#pragma unroll
            for (int m = 0; m < K_; m += 4) {
                a0 += __expf(Sc[(m + 0) * 577] + su[m + 0]);
                a1 += __expf(Sc[(m + 1) * 577] + su[m + 1]);
                a2 += __expf(Sc[(m + 2) * 577] + su[m + 2]);
                a3 += __expf(Sc[(m + 3) * 577] + su[m + 3]);
            }
            sv[n] = norm - __logf((a0 + a1) + (a2 + a3));
        }
        __syncthreads();
    }

    float invT = 1.f / (*Tp);
    ushort_t* Pb = P_all + (size_t)b * K_ * N_;
    for (int r = w; r < K_; r += 8) {
        float ur = su[r];
        const float* Sr = Sl + r * 577;
#pragma unroll
        for (int k = 0; k < 9; ++k) {
            int n0 = lane + 64 * k;
            float lp = Sr[n0] + ur + sv[n0] - norm;
            Pb[r * N_ + n0] = f2bf(__expf(lp * invT) + __expf(lp));
        }
    }
}

// ---------------------------------------------------------------- aggnorm
// One block per batch (256 thr): agg = f (128x576) x P^T, 9-step BK=64
// dbuf GEMM (unrolled, vmcnt(6)), fused block L2 normalize + store.
__global__ __launch_bounds__(256) void aggnorm_kernel(
    const ushort_t* __restrict__ f_all, const ushort_t* __restrict__ P_all,
    const unsigned* __restrict__ temp, void* __restrict__ out)
{
    __shared__ ushort_t Atile[2][128 * 64];  // F tiles
    __shared__ ushort_t Ptile[2][64 * 64];   // P tiles
    __shared__ float red[4];
    int b = blockIdx.x;
    const ushort_t* F = f_all + (size_t)b * D_ * N_;
    const ushort_t* P = P_all + (size_t)b * K_ * N_;
    int tid = threadIdx.x, w = tid >> 6, lane = tid & 63;
    int wr = w >> 1, wc = w & 1;
    int r16 = lane & 15, q = lane >> 4, kh = q * 8;

    int srow = tid >> 3;
    int cx = ((tid & 7) ^ (srow & 7)) * 8;
    const ushort_t* fg[4];
    const ushort_t* pg[2];
#pragma unroll
    for (int s = 0; s < 4; ++s)
        fg[s] = F + (size_t)(s * 32 + srow) * N_ + cx;
#pragma unroll
    for (int s = 0; s < 2; ++s)
        pg[s] = P + (size_t)(s * 32 + srow) * N_ + cx;

    f32x4 acc[4][2];
#pragma unroll
    for (int i = 0; i < 4; ++i)
#pragma unroll
        for (int j = 0; j < 2; ++j) acc[i][j] = f32x4{0.f, 0.f, 0.f, 0.f};

    int rowa = wr * 64 + r16;
    int rowp = wc * 32 + r16;
    int xr = (r16 & 7) * 8;

    auto stage = [&](int buf, int koff) {
#pragma unroll
        for (int s = 0; s < 4; ++s)
            cp16(fg[s] + koff, &Atile[buf][tid * 8 + s * 2048]);
#pragma unroll
        for (int s = 0; s < 2; ++s)
            cp16(pg[s] + koff, &Ptile[buf][tid * 8 + s * 2048]);
    };
    auto compute = [&](int cb) {
#pragma unroll
        for (int ks = 0; ks < 2; ++ks) {
            int ke = (ks * 32 + kh) ^ xr;
            short8 af[4], pf[2];
#pragma unroll
            for (int i = 0; i < 4; ++i)
                af[i] = *(const short8*)&Atile[cb][(rowa + i * 16) * 64 + ke];
#pragma unroll
            for (int j = 0; j < 2; ++j)
                pf[j] = *(const short8*)&Ptile[cb][(rowp + j * 16) * 64 + ke];
#pragma unroll
            for (int i = 0; i < 4; ++i)
#pragma unroll
                for (int j = 0; j < 2; ++j)
                    acc[i][j] = __builtin_amdgcn_mfma_f32_16x16x32_bf16(
                        af[i], pf[j], acc[i][j], 0, 0, 0);
        }
    };

    stage(0, 0);
#pragma unroll
    for (int kt = 0; kt < 9; ++kt) {
        int buf = kt & 1;
        if (kt < 8) {
            stage(buf ^ 1, (kt + 1) * 64);
            asm volatile("s_waitcnt vmcnt(6)" ::: "memory");
        } else {
            asm volatile("s_waitcnt vmcnt(0)" ::: "memory");
        }
        bar();
        compute(buf);
        bar();
    }

    float ssq = 0.f;
#pragma unroll
    for (int i = 0; i < 4; ++i)
#pragma unroll
        for (int j = 0; j < 2; ++j)
#pragma unroll
            for (int r = 0; r < 4; ++r) { float v = acc[i][j][r]; ssq += v * v; }
#pragma unroll
    for (int off = 32; off; off >>= 1) ssq += __shfl_xor(ssq, off);
    if (lane == 0) red[w] = ssq;
    __syncthreads();
    float tot = red[0] + red[1] + red[2] + red[3];
    float inv = 1.f / fmaxf(sqrtf(tot), 1e-12f);
    int flag = (temp[0] == 0x3F800000u) ? 1 : 0;
#pragma unroll
    for (int i = 0; i < 4; ++i) {
#pragma unroll
        for (int j = 0; j < 2; ++j) {
            int col = wc * 32 + j * 16 + r16;
#pragma unroll
            for (int r = 0; r < 4; ++r) {
                int row = wr * 64 + i * 16 + q * 4 + r;
                float v = acc[i][j][r] * inv;
                size_t idx = (size_t)b * D_ * K_ + (size_t)row * K_ + col;
                if (flag) ((float*)out)[idx] = v;
                else      ((ushort_t*)out)[idx] = f2bf(v);
            }
        }
    }
}

extern "C" void kernel_launch(void* const* d_in, const int* in_sizes, int n_in,
                              void* d_out, int out_size, void* d_ws, size_t ws_size,
                              hipStream_t stream) {
    const void* x    = d_in[0];
    const void* w1c  = d_in[1];
    const void* b1c  = d_in[2];
    const void* w2c  = d_in[3];
    const void* b2c  = d_in[4];
    const void* w1s  = d_in[5];
    const void* b1s  = d_in[6];
    const void* w2s  = d_in[7];
    const void* b2s  = d_in[8];
    const unsigned* temp = (const unsigned*)d_in[9];

    char* ws = (char*)d_ws;
    float* Tp = (float*)ws;
    ushort_t* Wb = (ushort_t*)(ws + 256);
    size_t offXt = 256 + (((size_t)WTOT_ * 2 + 255) & ~(size_t)255);
    ushort_t* Xt = (ushort_t*)(ws + offXt);
    size_t xtBytes = (size_t)B_ * N_ * C_ * 2;
    ushort_t* h  = (ushort_t*)(ws + offXt + xtBytes);   // (B*N, 1024) bf16
    // fbuf/sbuf/P alias the (dead after gemm1) Xt region
    size_t o0 = offXt;
    ushort_t* fbuf = (ushort_t*)(ws + o0);  o0 += (size_t)B_ * D_ * N_ * 2;
    float*    sbuf = (float*)(ws + o0);     o0 += (size_t)B_ * K_ * N_ * 4;
    ushort_t* Pws  = (ushort_t*)(ws + o0);  o0 += (size_t)B_ * K_ * N_ * 2;

    prep_kernel<<<dim3(TRB2_ + CVB4_), 256, 0, stream>>>(
        x, w1c, b1c, w2c, b2c, w1s, b1s, w2s, b2s, temp, Xt, Wb, Tp);
    gemm1_kernel<<<dim3(1152), 256, 0, stream>>>(Xt, Wb, Wb + OB1_, h);
    gemm2_kernel<<<dim3(5, B_, 2), 256, 0, stream>>>(Wb, h, fbuf, sbuf);
    sinkhorn_kernel<<<dim3(B_), 512, 0, stream>>>(sbuf, Tp, Pws);
    aggnorm_kernel<<<dim3(B_), 256, 0, stream>>>(fbuf, Pws, temp, (void*)d_out);
}